// Round 4
// baseline (80.371 us; speedup 1.0000x reference)
//
#include <hip/hip_runtime.h>
#include <cstdint>

// Ball query: B=8, N=4096, radius=0.2, nsample=32. Queries == sources.
// Output int32 (B,N,32): first 32 in-radius indices ascending, padded with
// the first match.
//
// NUMERICS (LOCKED, R8-verified absmax=0): expansion form f32,
//   sq  = (x*x + y*y) + z*z              -- plain, no FMA
//   dot = fma(qz,sz, fma(qy,sy, qx*sx))  -- FMA, K ascending
//   d2  = (sqq + sqs) - (dot + dot)
//   match = d2 < 0.04f
// R15: same ops now issue as v_pk_*_f32 (packed f32, 2 rounds per inst).
// Each 32-bit half of a packed op is the identical IEEE f32 operation in
// the identical order; subtract = pk_add with neg modifier (bit-identical
// to v_sub_f32). All in inline asm -- immune to -ffast-math. DO NOT CHANGE.
//
// R15 perf theory: R12 (1.9M loads) == R13 (0.63M loads) == R14 (0.71M)
// at ~38us kernel -> NOT load-bound. Invariant across all three: ~1.2-1.4M
// "query-rounds" (d2 + ballot + lane==k capture) ~ 72 cyc each -> the
// kernel is per-round VALU-machinery bound. R13's +1.9us pack kernel also
// proves dispatches serialize (no fill overlap). R15 attacks inst/round:
//  * v_pk_*_f32: one inst = two rounds' d2 (6 pk per 2 rounds vs 12 scalar);
//    packed sq (5 per 2 points vs 10). Q kept as {qx,qy},{qz,sqq} pairs,
//    broadcast via op_sel/op_sel_hi -> no register doubling.
//  * stepping lane-pointer: all 12 chunk loads use compile-time immediate
//    offsets (u*768 + {0,4,8} bytes <= 2312 < 4095), one 64-bit add/chunk.
//    Kills the per-load ((k<<6)+lane)*3 address rebuild (~30 inst/chunk).
//  * F[] is wave-uniform by construction (popcll of ballot) -> scalar
//    skip branches, s_min alldone; no readfirstlane.
//  * single buffer (prefetch proven neutral in R13/R14), saves ~24 VGPR.
// Structure kept from R14: 8 queries/wave shared scan, per-chunk uniform
// skip, prefix-free emit. 2048 blocks x 128 thr.

#define BQ_N    4096
#define BQ_B    8
#define BQ_NS   32
#define BQ_R2   0.04f
#define BQ_NC   16    // chunks of 256 points (4 rounds of 64)

typedef float v2f __attribute__((ext_vector_type(2)));

// Scalar sq for the wave's query points (original LOCKED asm).
__device__ __forceinline__ float sq_plain(float x, float y, float z) {
    float r, t;
    asm("v_mul_f32 %0, %2, %2\n\t"
        "v_mul_f32 %1, %3, %3\n\t"
        "v_add_f32 %0, %0, %1\n\t"
        "v_mul_f32 %1, %4, %4\n\t"
        "v_add_f32 %0, %0, %1"
        : "=&v"(r), "=&v"(t)
        : "v"(x), "v"(y), "v"(z));
    return r;
}

// Packed sq for two scan points: per-half identical op order
// (x*x + y*y) + z*z, plain mul/add.
__device__ __forceinline__ v2f sq2_plain(v2f x, v2f y, v2f z) {
    v2f r, t;
    asm("v_pk_mul_f32 %0, %2, %2 op_sel:[0,0] op_sel_hi:[1,1]\n\t"
        "v_pk_mul_f32 %1, %3, %3 op_sel:[0,0] op_sel_hi:[1,1]\n\t"
        "v_pk_add_f32 %0, %0, %1 op_sel:[0,0] op_sel_hi:[1,1]\n\t"
        "v_pk_mul_f32 %1, %4, %4 op_sel:[0,0] op_sel_hi:[1,1]\n\t"
        "v_pk_add_f32 %0, %0, %1 op_sel:[0,0] op_sel_hi:[1,1]"
        : "=&v"(r), "=&v"(t)
        : "v"(x), "v"(y), "v"(z));
    return r;
}

// Packed d2 for two consecutive rounds vs one query.
// qa = {qx, qy}, qb = {qz, sqq}; s* = {point_k comp, point_{k+1} comp}.
// Per half:  dot = fma(qz,sz, fma(qy,sy, qx*sx));
//            d2  = (sqq + sqs) - (dot + dot)     [sub via neg modifier]
__device__ __forceinline__ v2f d2_pk(v2f qa, v2f qb, v2f sx, v2f sy, v2f sz,
                                     v2f sq2) {
    v2f r, t;
    asm("v_pk_mul_f32 %0, %2, %4 op_sel:[0,0] op_sel_hi:[0,1]\n\t"
        "v_pk_fma_f32 %0, %2, %5, %0 op_sel:[1,0,0] op_sel_hi:[1,1,1]\n\t"
        "v_pk_fma_f32 %0, %3, %6, %0 op_sel:[0,0,0] op_sel_hi:[0,1,1]\n\t"
        "v_pk_add_f32 %0, %0, %0 op_sel:[0,0] op_sel_hi:[1,1]\n\t"
        "v_pk_add_f32 %1, %3, %7 op_sel:[1,0] op_sel_hi:[1,1]\n\t"
        "v_pk_add_f32 %0, %1, %0 op_sel:[0,0] op_sel_hi:[1,1] neg_lo:[0,1] neg_hi:[0,1]"
        : "=&v"(r), "=&v"(t)
        : "v"(qa), "v"(qb), "v"(sx), "v"(sy), "v"(sz), "v"(sq2));
    return r;
}

// Two rounds (k, k+1) for one query: ballots + lane==k capture of word and
// exclusive prefix. bal/f are wave-uniform (SGPR); captures are cndmask.
__device__ __forceinline__ void proc_pair(v2f qa, v2f qb, v2f sx, v2f sy,
                                          v2f sz, v2f sq2, int lane, int k,
                                          uint32_t& wlo, uint32_t& whi,
                                          int& p, int& f) {
    const v2f d2 = d2_pk(qa, qb, sx, sy, sz, sq2);
    const uint64_t b0 = __ballot(d2[0] < BQ_R2);        // round k
    if (lane == k)     { wlo = (uint32_t)b0; whi = (uint32_t)(b0 >> 32); p = f; }
    f += (int)__popcll(b0);
    const uint64_t b1 = __ballot(d2[1] < BQ_R2);        // round k+1
    if (lane == k + 1) { wlo = (uint32_t)b1; whi = (uint32_t)(b1 >> 32); p = f; }
    f += (int)__popcll(b1);
}

// Prefix-free emit: lane k holds round-k word and wpre (= matches before
// round k, captured during scan). Pure stores; padding only when total<32.
__device__ __forceinline__ void emit_query(int* __restrict__ orow, int lane,
                                           uint32_t wlo, uint32_t whi,
                                           int wpre, int total)
{
    const uint64_t word = ((uint64_t)whi << 32) | wlo;
    uint64_t w = word;
    int pos = wpre;                      // >=32 for overshoot rounds -> skipped
    while (w != 0ull && pos < BQ_NS) {
        const int bit = __builtin_ctzll(w);
        orow[pos] = (lane << 6) + bit;   // lane == round k; ascending order
        w &= (w - 1);
        ++pos;
    }
    if (total < BQ_NS) {                 // rare (queries with <32 neighbors)
        int first;
        const uint64_t nz = __ballot(word != 0ull);
        if (nz == 0ull) {
            first = BQ_N;   // defensive; self-match (|d2|<=2e-7) makes this unreachable
        } else {
            const int fl = __builtin_ctzll(nz);
            const uint64_t fw = __shfl(word, fl);
            first = (fl << 6) + __builtin_ctzll(fw);
        }
        if (lane >= total && lane < BQ_NS) orow[lane] = first;
    }
}

__global__ __launch_bounds__(128, 4)
void ball_query_kernel(const float* __restrict__ xyz, int* __restrict__ out)
{
    const int b    = blockIdx.x >> 8;            // 256 blocks per batch
    const int wq   = ((blockIdx.x & 255) << 4) + ((threadIdx.x >> 6) << 3);
    const int lane = threadIdx.x & 63;           // wave owns queries wq..wq+7
    const float* __restrict__ src = xyz + (size_t)b * BQ_N * 3;
    int* __restrict__ outb = out + (size_t)(b * BQ_N) * BQ_NS;

    // Wave's 8 query points as packed pairs {qx,qy}, {qz,sqq}.
    v2f Qa[8], Qb[8];
    #pragma unroll
    for (int j = 0; j < 8; ++j) {
        const int m = wq + j;
        const float x = src[3 * m + 0];
        const float y = src[3 * m + 1];
        const float z = src[3 * m + 2];
        Qa[j][0] = x; Qa[j][1] = y;
        Qb[j][0] = z; Qb[j][1] = sq_plain(x, y, z);
    }

    uint32_t Wlo[8] = {0,0,0,0,0,0,0,0};
    uint32_t Whi[8] = {0,0,0,0,0,0,0,0};
    int      P[8]   = {0,0,0,0,0,0,0,0};
    int      F[8]   = {0,0,0,0,0,0,0,0};   // wave-uniform -> SGPR

    // Stepping lane-pointer: chunk c round u component w lives at
    // lp[u*192 + w]; all 12 offsets are compile-time immediates (<= 2312B).
    const float* lp = src + lane * 3;

    for (int c = 0; c < BQ_NC; ++c) {
        // Load chunk: rounds (0,1) -> lo/hi of *01, rounds (2,3) -> *23.
        v2f X01, Y01, Z01, X23, Y23, Z23;
        X01[0] = lp[  0]; X01[1] = lp[192];
        Y01[0] = lp[  1]; Y01[1] = lp[193];
        Z01[0] = lp[  2]; Z01[1] = lp[194];
        X23[0] = lp[384]; X23[1] = lp[576];
        Y23[0] = lp[385]; Y23[1] = lp[577];
        Z23[0] = lp[386]; Z23[1] = lp[578];
        lp += 768;

        const v2f SQ01 = sq2_plain(X01, Y01, Z01);
        const v2f SQ23 = sq2_plain(X23, Y23, Z23);

        const int k0 = c << 2;
        #pragma unroll
        for (int j = 0; j < 8; ++j) {
            if (F[j] < BQ_NS) {          // wave-uniform -> scalar branch
                proc_pair(Qa[j], Qb[j], X01, Y01, Z01, SQ01, lane, k0,
                          Wlo[j], Whi[j], P[j], F[j]);
                proc_pair(Qa[j], Qb[j], X23, Y23, Z23, SQ23, lane, k0 + 2,
                          Wlo[j], Whi[j], P[j], F[j]);
            }
        }

        int m = F[0];
        #pragma unroll
        for (int j = 1; j < 8; ++j) m = min(m, F[j]);
        if (m >= BQ_NS) break;           // wave-uniform early exit
    }

    #pragma unroll
    for (int j = 0; j < 8; ++j)
        emit_query(outb + (size_t)(wq + j) * BQ_NS, lane,
                   Wlo[j], Whi[j], P[j], F[j]);
}

extern "C" void kernel_launch(void* const* d_in, const int* in_sizes, int n_in,
                              void* d_out, int out_size, void* d_ws, size_t ws_size,
                              hipStream_t stream)
{
    const float* xyz = (const float*)d_in[0];   // (8, 4096, 3) f32; d_in[1] unused
    int* out = (int*)d_out;                     // (8, 4096, 32) int32
    hipLaunchKernelGGL(ball_query_kernel, dim3(2048), dim3(128), 0, stream,
                       xyz, out);
}